// Round 1
// baseline (247.805 us; speedup 1.0000x reference)
//
#include <hip/hip_runtime.h>
#include <math.h>

#define BATCH 32

// ---------------------------------------------------------------- utilities
__device__ __forceinline__ float eluf(float v) { return v > 0.f ? v : expm1f(v); }
__device__ __forceinline__ float softplusf(float x) {
    return fmaxf(x, 0.f) + log1pf(expf(-fabsf(x)));
}
__device__ __forceinline__ float sigmoidf(float x) { return 1.f / (1.f + expf(-x)); }

// ---------------------------------------------------------------- zero stats
__global__ void zero_stats_kernel(float* stats) {
    stats[threadIdx.x] = 0.f;  // 512 threads, 512 floats (4 layers x 64ch x {sum,sumsq})
}

// ---------------------------------------------------------------- conv 3x3 stride 2 (VALID)
// grid = (B, 8 co-groups, z-tiles of 256 px), block = 256
// Each thread: one output pixel, 8 output channels. Weights are block-uniform -> SGPR.
// Also accumulates per-channel sum / sumsq of the RAW conv output into stats (atomics).
template <int CIN, int HIN, int WIN, int HOUT, int WOUT>
__global__ __launch_bounds__(256) void conv_s2_kernel(
    const float* __restrict__ in, const float* __restrict__ w,
    const float* __restrict__ bias, float* __restrict__ out,
    float* __restrict__ stats)
{
    const int b   = blockIdx.x;
    const int co0 = blockIdx.y * 8;
    const int px  = blockIdx.z * 256 + threadIdx.x;
    const bool active = px < HOUT * WOUT;
    const int p = active ? px : 0;
    const int y = p / WOUT, x = p % WOUT;

    const float* inb = in + (size_t)b * CIN * HIN * WIN + (2 * y) * WIN + 2 * x;

    float acc[8];
#pragma unroll
    for (int u = 0; u < 8; ++u) acc[u] = bias[co0 + u];

    for (int ci = 0; ci < CIN; ++ci) {
        float pch[9];
        const float* ip = inb + ci * HIN * WIN;
#pragma unroll
        for (int ky = 0; ky < 3; ++ky)
#pragma unroll
            for (int kx = 0; kx < 3; ++kx)
                pch[ky * 3 + kx] = ip[ky * WIN + kx];
        const float* wc = w + ((size_t)co0 * CIN + ci) * 9;
#pragma unroll
        for (int u = 0; u < 8; ++u)
#pragma unroll
            for (int j = 0; j < 9; ++j)
                acc[u] = fmaf(pch[j], wc[u * CIN * 9 + j], acc[u]);
    }

    __shared__ float red_s[4][8];
    __shared__ float red_q[4][8];
    const int lane = threadIdx.x & 63;
    const int wv   = threadIdx.x >> 6;

#pragma unroll
    for (int u = 0; u < 8; ++u) {
        float v = active ? acc[u] : 0.f;
        if (active)
            out[(((size_t)b * 64 + co0 + u) * HOUT + y) * WOUT + x] = v;
        float s = v, q = v * v;
#pragma unroll
        for (int off = 32; off > 0; off >>= 1) {
            s += __shfl_down(s, off);
            q += __shfl_down(q, off);
        }
        if (lane == 0) { red_s[wv][u] = s; red_q[wv][u] = q; }
    }
    __syncthreads();
    if (threadIdx.x < 16) {
        const int u = threadIdx.x >> 1;
        const int which = threadIdx.x & 1;
        float t;
        if (which)
            t = red_q[0][u] + red_q[1][u] + red_q[2][u] + red_q[3][u];
        else
            t = red_s[0][u] + red_s[1][u] + red_s[2][u] + red_s[3][u];
        atomicAdd(&stats[2 * (co0 + u) + which], t);
    }
}

// ---------------------------------------------------------------- bn + elu (in place)
// stats finished inline: mean = s/N, var = q/N - mean^2
template <int PLANE>
__global__ __launch_bounds__(256) void bnelu_kernel(
    float* __restrict__ h, const float* __restrict__ stats,
    const float* __restrict__ g, const float* __restrict__ be)
{
    const float invN = 1.f / (float)(BATCH * PLANE);
    const long long total = (long long)BATCH * 64 * PLANE;
    for (long long idx = (long long)blockIdx.x * blockDim.x + threadIdx.x; idx < total;
         idx += (long long)gridDim.x * blockDim.x) {
        int c = (int)((idx / PLANE) & 63);
        float s = stats[2 * c], q = stats[2 * c + 1];
        float m = s * invN;
        float var = fmaf(q, invN, -m * m);
        float a = g[c] * rsqrtf(var + 1e-5f);
        float bb = fmaf(-a, m, be[c]);
        float v = fmaf(a, h[idx], bb);
        h[idx] = eluf(v);
    }
}

// ---------------------------------------------------------------- head: 1x1 convs + params
// one block per batch image; x4[b] is 64x49 floats
__global__ __launch_bounds__(256) void head_kernel(
    const float* __restrict__ x4, const float* __restrict__ wp, const float* __restrict__ bp,
    const float* __restrict__ wz, const float* __restrict__ bz,
    const float* __restrict__ eps_scale, const float* __restrict__ eps_shift,
    float* __restrict__ params)
{
    __shared__ float xs[64 * 49];
    __shared__ float fe[64 * 49];
    __shared__ float zz[11 * 49];
    const int b = blockIdx.x, t = threadIdx.x;

    for (int i = t; i < 64 * 49; i += 256) xs[i] = x4[(size_t)b * 64 * 49 + i];
    __syncthreads();

    for (int i = t; i < 64 * 49; i += 256) {
        int co = i / 49, p = i % 49;
        float a = bp[co];
        for (int ci = 0; ci < 64; ++ci) a = fmaf(xs[ci * 49 + p], wp[co * 64 + ci], a);
        fe[i] = eluf(a);
    }
    __syncthreads();

    for (int i = t; i < 11 * 49; i += 256) {
        int co = i / 49, p = i % 49;
        float a = bz[co];
        for (int ci = 0; ci < 64; ++ci) a = fmaf(fe[ci * 49 + p], wz[co * 64 + ci], a);
        zz[i] = a;
    }
    __syncthreads();

    if (t < 49) {
        const int i = t / 7, j = t % 7;
        float es0 = eps_scale[((size_t)b * 49 + t) * 2 + 0];
        float es1 = eps_scale[((size_t)b * 49 + t) * 2 + 1];
        float eh0 = eps_shift[((size_t)b * 49 + t) * 2 + 0];
        float eh1 = eps_shift[((size_t)b * 49 + t) * 2 + 1];
        float zs0 = zz[3 * 49 + t] + softplusf(zz[5 * 49 + t]) * es0;
        float zs1 = zz[4 * 49 + t] + softplusf(zz[6 * 49 + t]) * es1;
        float zh0 = zz[7 * 49 + t] + softplusf(zz[9 * 49 + t]) * eh0;
        float zh1 = zz[8 * 49 + t] + softplusf(zz[10 * 49 + t]) * eh1;
        float th = sigmoidf(zs0) * 0.25f;           // 32/128
        float tw = sigmoidf(zs1) * 0.25f;
        float tx = ((float)i / 7.0f + sigmoidf(zh0) / 7.0f) * 2.f - 1.f;
        float ty = ((float)j / 7.0f + sigmoidf(zh1) / 7.0f) * 2.f - 1.f;
        float4* pp = (float4*)params;
        pp[b * 49 + t] = make_float4(th, tw, tx, ty);
    }
}

// ---------------------------------------------------------------- bilinear glimpse sampler
// one block per (b,k); 3 channels x 32x32 = 3072 outputs
__device__ __forceinline__ float tap(const float* __restrict__ im, int yy, int xx) {
    bool ok = (xx >= 0) & (xx < 128) & (yy >= 0) & (yy < 128);
    int yc = min(max(yy, 0), 127);
    int xc = min(max(xx, 0), 127);
    return ok ? im[yc * 128 + xc] : 0.f;
}

__global__ __launch_bounds__(256) void sampler_kernel(
    const float* __restrict__ img, const float* __restrict__ params,
    float* __restrict__ out)
{
    const int bk = blockIdx.x;       // b*49 + k
    const int b  = bk / 49;
    const float4 pr = ((const float4*)params)[bk];
    const float th = pr.x, tw = pr.y, tx = pr.z, ty = pr.w;

    for (int idx = threadIdx.x; idx < 3072; idx += 256) {
        const int c  = idx >> 10;
        const int gy = (idx >> 5) & 31;
        const int gx = idx & 31;
        float xb = (2.f * gx + 1.f) / 32.f - 1.f;
        float yb = (2.f * gy + 1.f) / 32.f - 1.f;
        float ixn = fmaf(tw, xb, ty);
        float iyn = fmaf(th, yb, tx);
        float px = ((ixn + 1.f) * 128.f - 1.f) * 0.5f;
        float py = ((iyn + 1.f) * 128.f - 1.f) * 0.5f;
        float x0f = floorf(px), y0f = floorf(py);
        float wx = px - x0f, wy = py - y0f;
        int x0 = (int)x0f, y0 = (int)y0f;
        const float* im = img + ((size_t)b * 3 + c) * 16384;
        float v00 = tap(im, y0, x0);
        float v01 = tap(im, y0, x0 + 1);
        float v10 = tap(im, y0 + 1, x0);
        float v11 = tap(im, y0 + 1, x0 + 1);
        float r = v00 * (1.f - wy) * (1.f - wx) + v01 * (1.f - wy) * wx +
                  v10 * wy * (1.f - wx)        + v11 * wy * wx;
        out[(size_t)bk * 3072 + idx] = r;
    }
}

// ---------------------------------------------------------------- launch
extern "C" void kernel_launch(void* const* d_in, const int* in_sizes, int n_in,
                              void* d_out, int out_size, void* d_ws, size_t ws_size,
                              hipStream_t stream)
{
    const float* img       = (const float*)d_in[0];
    const float* eps_scale = (const float*)d_in[1];
    const float* eps_shift = (const float*)d_in[2];
    const float* w1 = (const float*)d_in[3],  *b1 = (const float*)d_in[4];
    const float* g1 = (const float*)d_in[5],  *be1 = (const float*)d_in[6];
    const float* w2 = (const float*)d_in[7],  *b2 = (const float*)d_in[8];
    const float* g2 = (const float*)d_in[9],  *be2 = (const float*)d_in[10];
    const float* w3 = (const float*)d_in[11], *b3 = (const float*)d_in[12];
    const float* g3 = (const float*)d_in[13], *be3 = (const float*)d_in[14];
    const float* w4 = (const float*)d_in[15], *b4 = (const float*)d_in[16];
    const float* g4 = (const float*)d_in[17], *be4 = (const float*)d_in[18];
    const float* wp = (const float*)d_in[19], *bp = (const float*)d_in[20];
    const float* wz = (const float*)d_in[21], *bz = (const float*)d_in[22];

    float* ws     = (float*)d_ws;
    float* stats  = ws;              // 512 floats: 4 layers x 64ch x {sum, sumsq}
    float* params = ws + 512;        // 32*49*4 = 6272 floats
    float* h1     = ws + 6784;                     // 32*64*63*63
    float* h2     = h1 + (size_t)32 * 64 * 63 * 63; // 32*64*31*31
    float* h3     = h2 + (size_t)32 * 64 * 31 * 31; // 32*64*15*15
    float* h4     = h3 + (size_t)32 * 64 * 15 * 15; // 32*64*7*7

    float* outp = (float*)d_out;

    zero_stats_kernel<<<1, 512, 0, stream>>>(stats);

    conv_s2_kernel<3, 128, 128, 63, 63><<<dim3(32, 8, 16), 256, 0, stream>>>(img, w1, b1, h1, stats + 0);
    bnelu_kernel<63 * 63><<<2048, 256, 0, stream>>>(h1, stats + 0, g1, be1);

    conv_s2_kernel<64, 63, 63, 31, 31><<<dim3(32, 8, 4), 256, 0, stream>>>(h1, w2, b2, h2, stats + 128);
    bnelu_kernel<31 * 31><<<2048, 256, 0, stream>>>(h2, stats + 128, g2, be2);

    conv_s2_kernel<64, 31, 31, 15, 15><<<dim3(32, 8, 1), 256, 0, stream>>>(h2, w3, b3, h3, stats + 256);
    bnelu_kernel<15 * 15><<<1800, 256, 0, stream>>>(h3, stats + 256, g3, be3);

    conv_s2_kernel<64, 15, 15, 7, 7><<<dim3(32, 8, 1), 256, 0, stream>>>(h3, w4, b4, h4, stats + 384);
    bnelu_kernel<7 * 7><<<392, 256, 0, stream>>>(h4, stats + 384, g4, be4);

    head_kernel<<<32, 256, 0, stream>>>(h4, wp, bp, wz, bz, eps_scale, eps_shift, params);

    sampler_kernel<<<1568, 256, 0, stream>>>(img, params, outp);
}